// Round 8
// baseline (300.636 us; speedup 1.0000x reference)
//
#include <hip/hip_runtime.h>
#include <hip/hip_fp16.h>

#define CH 64
#define LOG2E  1.44269504f
#define MLOG2E -1.44269504f
#define PROJ_BLOCKS 1024

// v_exp_f32 computes 2^x (ISA §3). Pure op -> schedulable.
__device__ __forceinline__ float exp2fast(float x) {
    float r; asm("v_exp_f32 %0, %1" : "=v"(r) : "v"(x)); return r;
}

// cubic Chebyshev fit of e^s on s in [0,1], abs err <= 5.4e-4
#define EXPP_D0 0.9994851f
#define EXPP_D1 1.0160896f
#define EXPP_D2 0.4230492f
#define EXPP_D3 0.2790848f
__device__ __forceinline__ float exp01_poly(float s) {
    return fmaf(fmaf(fmaf(EXPP_D3, s, EXPP_D2), s, EXPP_D1), s, EXPP_D0);
}

// ---------------------------------------------------------------------------
// K1 (grid-partitioned fusion):
//  blocks [0, PROJ_BLOCKS):  per-node minmax norm + three 64x64 GEMVs
//                            -> lr = half2(l,r), residual into d_out
//  blocks [PROJ_BLOCKS, ..): degree histogram; atomicAdd return value =
//                            edge's rank in its dst segment (atomic-free scatter)
// Disjoint data -> the two phases truly overlap inside one launch.
// ---------------------------------------------------------------------------
__global__ __launch_bounds__(256) void proj_count_kernel(
    const float* __restrict__ nd,
    const float* __restrict__ W1, const float* __restrict__ b1,
    const float* __restrict__ W2, const float* __restrict__ b2,
    const float* __restrict__ Wr, const float* __restrict__ br,
    __half2* __restrict__ lr, float* __restrict__ hres,
    const int* __restrict__ dst, int* __restrict__ deg,
    int* __restrict__ rank, int N, int E)
{
    if (blockIdx.x >= PROJ_BLOCKS) {
        const int stride = (gridDim.x - PROJ_BLOCKS) * 256;
        for (int i = (blockIdx.x - PROJ_BLOCKS) * 256 + threadIdx.x; i < E;
             i += stride) {
            rank[i] = atomicAdd(&deg[dst[i]], 1);
        }
        return;
    }

    __shared__ __align__(16) float xs[4][CH];
    const int lane = threadIdx.x & 63;
    const int wid  = threadIdx.x >> 6;

    float w1[CH], w2[CH], wr[CH];
#pragma unroll
    for (int i = 0; i < CH; ++i) {
        w1[i] = W1[i * CH + lane];
        w2[i] = W2[i * CH + lane];
        wr[i] = Wr[i * CH + lane];
    }
    const float bb1 = b1[lane], bb2 = b2[lane], bbr = br[lane];

    const int nwave = PROJ_BLOCKS * 4;
    for (int node = blockIdx.x * 4 + wid; node < N; node += nwave) {
        const unsigned row = (unsigned)node * CH;
        float v = nd[row + lane];
        float mn = v, mx = v;
#pragma unroll
        for (int off = 32; off; off >>= 1) {
            mn = fminf(mn, __shfl_xor(mn, off));
            mx = fmaxf(mx, __shfl_xor(mx, off));
        }
        float x = (v - mn) / (mx - mn + 1e-5f);
        xs[wid][lane] = x;
        float a1 = bb1, a2 = bb2, a3 = bbr;
        const float4* x4 = reinterpret_cast<const float4*>(&xs[wid][0]);
#pragma unroll
        for (int k = 0; k < CH / 4; ++k) {
            float4 xv = x4[k];
            a1 = fmaf(xv.x, w1[4*k+0], a1);
            a1 = fmaf(xv.y, w1[4*k+1], a1);
            a1 = fmaf(xv.z, w1[4*k+2], a1);
            a1 = fmaf(xv.w, w1[4*k+3], a1);
            a2 = fmaf(xv.x, w2[4*k+0], a2);
            a2 = fmaf(xv.y, w2[4*k+1], a2);
            a2 = fmaf(xv.z, w2[4*k+2], a2);
            a2 = fmaf(xv.w, w2[4*k+3], a2);
            a3 = fmaf(xv.x, wr[4*k+0], a3);
            a3 = fmaf(xv.y, wr[4*k+1], a3);
            a3 = fmaf(xv.z, wr[4*k+2], a3);
            a3 = fmaf(xv.w, wr[4*k+3], a3);
        }
        lr[row + lane]   = __floats2half2_rn(a1, a2);
        hres[row + lane] = a3;
    }
}

// ---------------------------------------------------------------------------
// Single-launch exclusive scan (decoupled lookback, CUB-style).
// Ticket ordering guarantees every predecessor chunk's block has already
// STARTED (took an earlier ticket inside the kernel) -> no deadlock; waves
// are never preempted, so predecessors always finish. Device-scope
// acquire/release atomics per XCD non-coherence rules.
// flag: 0=invalid, 1=aggregate ready, 2=prefix ready.
// ---------------------------------------------------------------------------
__global__ __launch_bounds__(256) void scan_kernel(
    const int* __restrict__ deg, int* __restrict__ rowptr,
    int* __restrict__ agg, int* __restrict__ pre, int* __restrict__ flag,
    int* __restrict__ ticket, int N, int total)
{
    __shared__ int chunk;
    __shared__ int ws[4];
    __shared__ int prefix_sh;
    if (threadIdx.x == 0) chunk = atomicAdd(ticket, 1);
    __syncthreads();
    const int b = chunk;
    const int i = b * 256 + threadIdx.x;
    const int lane = threadIdx.x & 63, wid = threadIdx.x >> 6;
    int v = (i < N) ? deg[i] : 0;
    int s = v;
#pragma unroll
    for (int off = 1; off < 64; off <<= 1) {
        int t = __shfl_up(s, off);
        if (lane >= off) s += t;
    }
    if (lane == 63) ws[wid] = s;
    __syncthreads();
    int woff = 0;
    for (int w = 0; w < wid; ++w) woff += ws[w];
    const int blocksum = ws[0] + ws[1] + ws[2] + ws[3];

    if (threadIdx.x == 0) {
        __hip_atomic_store(&agg[b], blocksum, __ATOMIC_RELEASE, __HIP_MEMORY_SCOPE_AGENT);
        __hip_atomic_store(&flag[b], 1, __ATOMIC_RELEASE, __HIP_MEMORY_SCOPE_AGENT);
        int running = 0;
        if (b > 0) {
            int j = b - 1;
            while (true) {
                int f = __hip_atomic_load(&flag[j], __ATOMIC_ACQUIRE, __HIP_MEMORY_SCOPE_AGENT);
                if (f == 2) {
                    running += __hip_atomic_load(&pre[j], __ATOMIC_ACQUIRE, __HIP_MEMORY_SCOPE_AGENT);
                    break;
                } else if (f == 1) {
                    running += __hip_atomic_load(&agg[j], __ATOMIC_ACQUIRE, __HIP_MEMORY_SCOPE_AGENT);
                    if (j == 0) break;
                    --j;
                }
            }
        }
        __hip_atomic_store(&pre[b], running + blocksum, __ATOMIC_RELEASE, __HIP_MEMORY_SCOPE_AGENT);
        __hip_atomic_store(&flag[b], 2, __ATOMIC_RELEASE, __HIP_MEMORY_SCOPE_AGENT);
        prefix_sh = running;
    }
    __syncthreads();
    const int excl = prefix_sh + woff + s - v;
    if (i < N) rowptr[i] = excl;
    if (b == 0 && threadIdx.x == 0) rowptr[N] = total;
}

__global__ void scatter_kernel(const int* __restrict__ src,
                               const int* __restrict__ dst,
                               const int* __restrict__ rank,
                               const int* __restrict__ rowptr,
                               int* __restrict__ col, int E)
{
    for (int i = blockIdx.x * blockDim.x + threadIdx.x; i < E;
         i += gridDim.x * blockDim.x) {
        col[rowptr[dst[i]] + rank[i]] = src[i];
    }
}

// ---------------------------------------------------------------------------
// Edge batch: gather U half2 rows (ILP=U), then the weight:
//   s = rcp(1 + 2^(fma(x, -log2e, nd)))   (sigmoid, 1 exp2 + 1 rcp)
//   w = cubic_poly(s)                      (replaces second exp2 -> 3 FMA)
// Exact tails 16/8/4/2/1 (wave-uniform) -> zero padded work.
// ---------------------------------------------------------------------------
#define EDGE_BATCH(U_, TBL_, STEP_)                                          \
    {                                                                        \
        __half2 hb[U_];                                                      \
        _Pragma("unroll")                                                    \
        for (int u = 0; u < (U_); ++u) {                                     \
            int s_ = __builtin_amdgcn_readlane(myc, j + u);                  \
            hb[u] = TBL_[(unsigned)(s_ * CH) + lane];                        \
        }                                                                    \
        _Pragma("unroll")                                                    \
        for (int u = 0; u < (U_); ++u) { STEP_(hb[u]); }                     \
        j += (U_);                                                           \
    }

// ---------------------------------------------------------------------------
// Pass A: w = exp(sig(l_s+l_d)); denL = sum w; acc = sum r_s*w; ft_r = acc/denL
// Self-loop analytic; denR deferred to passB.
// ---------------------------------------------------------------------------
__global__ __launch_bounds__(256) void passA_kernel(
    const __half2* __restrict__ lr,
    const int* __restrict__ rowptr, const int* __restrict__ col,
    __half2* __restrict__ rf, int N)
{
    const int node = blockIdx.x * 4 + (threadIdx.x >> 6);
    const int lane = threadIdx.x & 63;
    if (node >= N) return;
    const unsigned row = (unsigned)node * CH;
    const float2 own = __half22float2(lr[row + lane]);
    const float l_d = own.x, r_d = own.y;
    const float nl_d = MLOG2E * l_d;
    const int beg = rowptr[node], end = rowptr[node + 1];

    float wl = exp01_poly(__builtin_amdgcn_rcpf(1.f + exp2fast(2.f * nl_d)));
    float denL = wl, acc = r_d * wl;

#define A_STEP(H_) {                                                         \
        float2 f = __half22float2(H_);                                       \
        float sg = __builtin_amdgcn_rcpf(1.f + exp2fast(fmaf(f.x, MLOG2E, nl_d))); \
        float w  = exp01_poly(sg);                                           \
        denL += w; acc = fmaf(f.y, w, acc); }

    int e = beg;
    while (e < end) {
        int cnt = end - e; if (cnt > 64) cnt = 64;
        int idx = e + lane; if (idx >= end) idx = end - 1;
        const int myc = col[idx];
        int j = 0;
        int nfull = cnt >> 4;
        for (int b = 0; b < nfull; ++b) EDGE_BATCH(16, lr, A_STEP)
        if (cnt & 8) EDGE_BATCH(8, lr, A_STEP)
        if (cnt & 4) EDGE_BATCH(4, lr, A_STEP)
        if (cnt & 2) EDGE_BATCH(2, lr, A_STEP)
        if (cnt & 1) EDGE_BATCH(1, lr, A_STEP)
        e += cnt;
    }
    rf[row + lane] = __floats2half2_rn(r_d, acc / denL);  // (r, ft_r)
}

// ---------------------------------------------------------------------------
// Pass B: numerator AND denominator in one loop; out = m0*acc/dR + hres.
// ---------------------------------------------------------------------------
__global__ __launch_bounds__(256) void passB_kernel(
    const __half2* __restrict__ rf,
    const int* __restrict__ rowptr, const int* __restrict__ col,
    const float* __restrict__ m0, float* __restrict__ out, int N)
{
    const int node = blockIdx.x * 4 + (threadIdx.x >> 6);
    const int lane = threadIdx.x & 63;
    if (node >= N) return;
    const unsigned row = (unsigned)node * CH;
    const float2 own = __half22float2(rf[row + lane]);
    const float r_d = own.x, f_own = own.y;
    const float nr_d = MLOG2E * r_d;
    const int beg = rowptr[node], end = rowptr[node + 1];

    float wsl = exp01_poly(__builtin_amdgcn_rcpf(1.f + exp2fast(2.f * nr_d)));
    float dR = wsl, acc = f_own * wsl;

#define B_STEP(H_) {                                                         \
        float2 f = __half22float2(H_);                                       \
        float sg = __builtin_amdgcn_rcpf(1.f + exp2fast(fmaf(f.x, MLOG2E, nr_d))); \
        float w  = exp01_poly(sg);                                           \
        dR += w; acc = fmaf(f.y, w, acc); }

    int e = beg;
    while (e < end) {
        int cnt = end - e; if (cnt > 64) cnt = 64;
        int idx = e + lane; if (idx >= end) idx = end - 1;
        const int myc = col[idx];
        int j = 0;
        int nfull = cnt >> 4;
        for (int b = 0; b < nfull; ++b) EDGE_BATCH(16, rf, B_STEP)
        if (cnt & 8) EDGE_BATCH(8, rf, B_STEP)
        if (cnt & 4) EDGE_BATCH(4, rf, B_STEP)
        if (cnt & 2) EDGE_BATCH(2, rf, B_STEP)
        if (cnt & 1) EDGE_BATCH(1, rf, B_STEP)
        e += cnt;
    }
    out[row + lane] = fmaf(m0[lane], acc / dR, out[row + lane]);
}

// ---------------------------------------------------------------------------
extern "C" void kernel_launch(void* const* d_in, const int* in_sizes, int n_in,
                              void* d_out, int out_size, void* d_ws, size_t ws_size,
                              hipStream_t stream)
{
    const float* ndata = (const float*)d_in[0];
    const int*   src   = (const int*)d_in[1];
    const int*   dst   = (const int*)d_in[2];
    const float* W1    = (const float*)d_in[3];
    const float* b1    = (const float*)d_in[4];
    const float* W2    = (const float*)d_in[5];
    const float* b2    = (const float*)d_in[6];
    const float* Wr    = (const float*)d_in[7];
    const float* br    = (const float*)d_in[8];
    const float* m     = (const float*)d_in[9];   // [3,8,8]; m[0] flat = 64
    float* out = (float*)d_out;

    const int N = in_sizes[0] / CH;
    const int E = in_sizes[1];
    const int nbk = (N + 255) / 256;

    char* ws = (char*)d_ws;
    size_t off = 0;
    auto alloc = [&](size_t bytes) -> void* {
        void* p = ws + off;
        off = (off + bytes + 255) & ~(size_t)255;
        return p;
    };
    __half2* lr   = (__half2*)alloc((size_t)N * CH * 4);
    __half2* rf   = (__half2*)alloc((size_t)N * CH * 4);
    // zero-init region: deg + flag + ticket contiguous (one memset)
    int*   deg    = (int*)alloc((size_t)(N + nbk + 1) * 4);
    int*   flag   = deg + N;
    int*   ticket = deg + N + nbk;
    size_t zbytes = (size_t)(N + nbk + 1) * 4;
    int*   agg    = (int*)alloc((size_t)nbk * 4);
    int*   pre    = (int*)alloc((size_t)nbk * 4);
    int*   rowptr = (int*)alloc((size_t)(N + 1) * 4);
    int*   rank   = (int*)alloc((size_t)E * 4);
    int*   col    = (int*)alloc((size_t)E * 4);

    hipMemsetAsync(deg, 0, zbytes, stream);
    proj_count_kernel<<<PROJ_BLOCKS + 2048, 256, 0, stream>>>(
        ndata, W1, b1, W2, b2, Wr, br, lr, out, dst, deg, rank, N, E);
    scan_kernel<<<nbk, 256, 0, stream>>>(deg, rowptr, agg, pre, flag, ticket,
                                         N, E);
    scatter_kernel<<<2048, 256, 0, stream>>>(src, dst, rank, rowptr, col, E);
    int nb = (N + 3) / 4;
    passA_kernel<<<nb, 256, 0, stream>>>(lr, rowptr, col, rf, N);
    passB_kernel<<<nb, 256, 0, stream>>>(rf, rowptr, col, m, out, N);
}

// Round 9
// 232.127 us; speedup vs baseline: 1.2951x; 1.2951x over previous
//
#include <hip/hip_runtime.h>
#include <hip/hip_fp16.h>

#define CH 64
#define LOG2E  1.44269504f
#define MLOG2E -1.44269504f
#define PROJ_BLOCKS 1024

// v_exp_f32 computes 2^x (ISA §3). Pure op -> schedulable.
__device__ __forceinline__ float exp2fast(float x) {
    float r; asm("v_exp_f32 %0, %1" : "=v"(r) : "v"(x)); return r;
}

// cubic Chebyshev fit of e^s on s in [0,1], abs err <= 5.4e-4
#define EXPP_D0 0.9994851f
#define EXPP_D1 1.0160896f
#define EXPP_D2 0.4230492f
#define EXPP_D3 0.2790848f
__device__ __forceinline__ float exp01_poly(float s) {
    return fmaf(fmaf(fmaf(EXPP_D3, s, EXPP_D2), s, EXPP_D1), s, EXPP_D0);
}

// ---------------------------------------------------------------------------
// K1 (grid-partitioned fusion):
//  blocks [0, PROJ_BLOCKS):  per-node minmax norm + three 64x64 GEMVs
//                            -> lr = half2(l,r), residual into d_out
//  blocks [PROJ_BLOCKS, ..): degree histogram; atomicAdd return value =
//                            edge's rank in its dst segment
// ---------------------------------------------------------------------------
__global__ __launch_bounds__(256) void proj_count_kernel(
    const float* __restrict__ nd,
    const float* __restrict__ W1, const float* __restrict__ b1,
    const float* __restrict__ W2, const float* __restrict__ b2,
    const float* __restrict__ Wr, const float* __restrict__ br,
    __half2* __restrict__ lr, float* __restrict__ hres,
    const int* __restrict__ dst, int* __restrict__ deg,
    int* __restrict__ rank, int N, int E)
{
    if (blockIdx.x >= PROJ_BLOCKS) {
        const int stride = (gridDim.x - PROJ_BLOCKS) * 256;
        for (int i = (blockIdx.x - PROJ_BLOCKS) * 256 + threadIdx.x; i < E;
             i += stride) {
            rank[i] = atomicAdd(&deg[dst[i]], 1);
        }
        return;
    }

    __shared__ __align__(16) float xs[4][CH];
    const int lane = threadIdx.x & 63;
    const int wid  = threadIdx.x >> 6;

    float w1[CH], w2[CH], wr[CH];
#pragma unroll
    for (int i = 0; i < CH; ++i) {
        w1[i] = W1[i * CH + lane];
        w2[i] = W2[i * CH + lane];
        wr[i] = Wr[i * CH + lane];
    }
    const float bb1 = b1[lane], bb2 = b2[lane], bbr = br[lane];

    const int nwave = PROJ_BLOCKS * 4;
    for (int node = blockIdx.x * 4 + wid; node < N; node += nwave) {
        const unsigned row = (unsigned)node * CH;
        float v = nd[row + lane];
        float mn = v, mx = v;
#pragma unroll
        for (int off = 32; off; off >>= 1) {
            mn = fminf(mn, __shfl_xor(mn, off));
            mx = fmaxf(mx, __shfl_xor(mx, off));
        }
        float x = (v - mn) / (mx - mn + 1e-5f);
        xs[wid][lane] = x;
        float a1 = bb1, a2 = bb2, a3 = bbr;
        const float4* x4 = reinterpret_cast<const float4*>(&xs[wid][0]);
#pragma unroll
        for (int k = 0; k < CH / 4; ++k) {
            float4 xv = x4[k];
            a1 = fmaf(xv.x, w1[4*k+0], a1);
            a1 = fmaf(xv.y, w1[4*k+1], a1);
            a1 = fmaf(xv.z, w1[4*k+2], a1);
            a1 = fmaf(xv.w, w1[4*k+3], a1);
            a2 = fmaf(xv.x, w2[4*k+0], a2);
            a2 = fmaf(xv.y, w2[4*k+1], a2);
            a2 = fmaf(xv.z, w2[4*k+2], a2);
            a2 = fmaf(xv.w, w2[4*k+3], a2);
            a3 = fmaf(xv.x, wr[4*k+0], a3);
            a3 = fmaf(xv.y, wr[4*k+1], a3);
            a3 = fmaf(xv.z, wr[4*k+2], a3);
            a3 = fmaf(xv.w, wr[4*k+3], a3);
        }
        lr[row + lane]   = __floats2half2_rn(a1, a2);
        hres[row + lane] = a3;
    }
}

// ---------------------------------------------------------------------------
// CSR build: 3-kernel multi-block exclusive scan (measured ~6 us total)
// + atomic-free scatter. (Decoupled-lookback single-kernel scan REGRESSED:
// cross-XCD flag polling = 78 us of spin. Keep the simple trio.)
// ---------------------------------------------------------------------------
__global__ __launch_bounds__(256) void bsum_kernel(
    const int* __restrict__ deg, int* __restrict__ bsum, int N)
{
    __shared__ int ws[4];
    int i = blockIdx.x * 256 + threadIdx.x;
    int lane = threadIdx.x & 63, wid = threadIdx.x >> 6;
    int v = (i < N) ? deg[i] : 0;
#pragma unroll
    for (int off = 32; off; off >>= 1) v += __shfl_xor(v, off);
    if (lane == 0) ws[wid] = v;
    __syncthreads();
    if (threadIdx.x == 0) bsum[blockIdx.x] = ws[0] + ws[1] + ws[2] + ws[3];
}

__global__ __launch_bounds__(64) void bscan_kernel(int* __restrict__ bsum, int nb)
{
    int lane = threadIdx.x;
    int carry = 0;
    for (int base = 0; base < nb; base += 64) {
        int i = base + lane;
        int v = (i < nb) ? bsum[i] : 0;
        int s = v;
#pragma unroll
        for (int off = 1; off < 64; off <<= 1) {
            int t = __shfl_up(s, off);
            if (lane >= off) s += t;
        }
        if (i < nb) bsum[i] = carry + s - v;   // exclusive
        carry += __shfl(s, 63);
    }
}

__global__ __launch_bounds__(256) void apply_kernel(
    const int* __restrict__ deg, const int* __restrict__ bsum,
    int* __restrict__ rowptr, int N, int total)
{
    __shared__ int ws[4];
    int i = blockIdx.x * 256 + threadIdx.x;
    int lane = threadIdx.x & 63, wid = threadIdx.x >> 6;
    int v = (i < N) ? deg[i] : 0;
    int s = v;
#pragma unroll
    for (int off = 1; off < 64; off <<= 1) {
        int t = __shfl_up(s, off);
        if (lane >= off) s += t;
    }
    if (lane == 63) ws[wid] = s;
    __syncthreads();
    int woff = 0;
    for (int w = 0; w < wid; ++w) woff += ws[w];
    int excl = bsum[blockIdx.x] + woff + s - v;
    if (i < N) rowptr[i] = excl;
    if (blockIdx.x == 0 && threadIdx.x == 0) rowptr[N] = total;
}

__global__ void scatter_kernel(const int* __restrict__ src,
                               const int* __restrict__ dst,
                               const int* __restrict__ rank,
                               const int* __restrict__ rowptr,
                               int* __restrict__ col, int E)
{
    for (int i = blockIdx.x * blockDim.x + threadIdx.x; i < E;
         i += gridDim.x * blockDim.x) {
        col[rowptr[dst[i]] + rank[i]] = src[i];
    }
}

// ---------------------------------------------------------------------------
// Edge batch: gather U half2 rows (ILP=U), then the weight:
//   s = rcp(1 + 2^(fma(x, -log2e, nd)))   (sigmoid, 1 exp2 + 1 rcp)
//   w = cubic_poly(s)                      (second exp -> 3 FMA)
// Exact tails 16/8/4/2/1 (wave-uniform) -> zero padded work.
// ---------------------------------------------------------------------------
#define EDGE_BATCH(U_, TBL_, STEP_)                                          \
    {                                                                        \
        __half2 hb[U_];                                                      \
        _Pragma("unroll")                                                    \
        for (int u = 0; u < (U_); ++u) {                                     \
            int s_ = __builtin_amdgcn_readlane(myc, j + u);                  \
            hb[u] = TBL_[(unsigned)(s_ * CH) + lane];                        \
        }                                                                    \
        _Pragma("unroll")                                                    \
        for (int u = 0; u < (U_); ++u) { STEP_(hb[u]); }                     \
        j += (U_);                                                           \
    }

// ---------------------------------------------------------------------------
// Pass A: w = exp(sig(l_s+l_d)); denL = sum w; acc = sum r_s*w; ft_r = acc/denL
// Self-loop analytic; denR deferred to passB.
// ---------------------------------------------------------------------------
__global__ __launch_bounds__(256) void passA_kernel(
    const __half2* __restrict__ lr,
    const int* __restrict__ rowptr, const int* __restrict__ col,
    __half2* __restrict__ rf, int N)
{
    const int node = blockIdx.x * 4 + (threadIdx.x >> 6);
    const int lane = threadIdx.x & 63;
    if (node >= N) return;
    const unsigned row = (unsigned)node * CH;
    const float2 own = __half22float2(lr[row + lane]);
    const float l_d = own.x, r_d = own.y;
    const float nl_d = MLOG2E * l_d;
    const int beg = rowptr[node], end = rowptr[node + 1];

    float wl = exp01_poly(__builtin_amdgcn_rcpf(1.f + exp2fast(2.f * nl_d)));
    float denL = wl, acc = r_d * wl;

#define A_STEP(H_) {                                                         \
        float2 f = __half22float2(H_);                                       \
        float sg = __builtin_amdgcn_rcpf(1.f + exp2fast(fmaf(f.x, MLOG2E, nl_d))); \
        float w  = exp01_poly(sg);                                           \
        denL += w; acc = fmaf(f.y, w, acc); }

    int e = beg;
    while (e < end) {
        int cnt = end - e; if (cnt > 64) cnt = 64;
        int idx = e + lane; if (idx >= end) idx = end - 1;
        const int myc = col[idx];
        int j = 0;
        int nfull = cnt >> 4;
        for (int b = 0; b < nfull; ++b) EDGE_BATCH(16, lr, A_STEP)
        if (cnt & 8) EDGE_BATCH(8, lr, A_STEP)
        if (cnt & 4) EDGE_BATCH(4, lr, A_STEP)
        if (cnt & 2) EDGE_BATCH(2, lr, A_STEP)
        if (cnt & 1) EDGE_BATCH(1, lr, A_STEP)
        e += cnt;
    }
    rf[row + lane] = __floats2half2_rn(r_d, acc / denL);  // (r, ft_r)
}

// ---------------------------------------------------------------------------
// Pass B: numerator AND denominator in one loop; out = m0*acc/dR + hres.
// ---------------------------------------------------------------------------
__global__ __launch_bounds__(256) void passB_kernel(
    const __half2* __restrict__ rf,
    const int* __restrict__ rowptr, const int* __restrict__ col,
    const float* __restrict__ m0, float* __restrict__ out, int N)
{
    const int node = blockIdx.x * 4 + (threadIdx.x >> 6);
    const int lane = threadIdx.x & 63;
    if (node >= N) return;
    const unsigned row = (unsigned)node * CH;
    const float2 own = __half22float2(rf[row + lane]);
    const float r_d = own.x, f_own = own.y;
    const float nr_d = MLOG2E * r_d;
    const int beg = rowptr[node], end = rowptr[node + 1];

    float wsl = exp01_poly(__builtin_amdgcn_rcpf(1.f + exp2fast(2.f * nr_d)));
    float dR = wsl, acc = f_own * wsl;

#define B_STEP(H_) {                                                         \
        float2 f = __half22float2(H_);                                       \
        float sg = __builtin_amdgcn_rcpf(1.f + exp2fast(fmaf(f.x, MLOG2E, nr_d))); \
        float w  = exp01_poly(sg);                                           \
        dR += w; acc = fmaf(f.y, w, acc); }

    int e = beg;
    while (e < end) {
        int cnt = end - e; if (cnt > 64) cnt = 64;
        int idx = e + lane; if (idx >= end) idx = end - 1;
        const int myc = col[idx];
        int j = 0;
        int nfull = cnt >> 4;
        for (int b = 0; b < nfull; ++b) EDGE_BATCH(16, rf, B_STEP)
        if (cnt & 8) EDGE_BATCH(8, rf, B_STEP)
        if (cnt & 4) EDGE_BATCH(4, rf, B_STEP)
        if (cnt & 2) EDGE_BATCH(2, rf, B_STEP)
        if (cnt & 1) EDGE_BATCH(1, rf, B_STEP)
        e += cnt;
    }
    out[row + lane] = fmaf(m0[lane], acc / dR, out[row + lane]);
}

// ---------------------------------------------------------------------------
extern "C" void kernel_launch(void* const* d_in, const int* in_sizes, int n_in,
                              void* d_out, int out_size, void* d_ws, size_t ws_size,
                              hipStream_t stream)
{
    const float* ndata = (const float*)d_in[0];
    const int*   src   = (const int*)d_in[1];
    const int*   dst   = (const int*)d_in[2];
    const float* W1    = (const float*)d_in[3];
    const float* b1    = (const float*)d_in[4];
    const float* W2    = (const float*)d_in[5];
    const float* b2    = (const float*)d_in[6];
    const float* Wr    = (const float*)d_in[7];
    const float* br    = (const float*)d_in[8];
    const float* m     = (const float*)d_in[9];   // [3,8,8]; m[0] flat = 64
    float* out = (float*)d_out;

    const int N = in_sizes[0] / CH;
    const int E = in_sizes[1];
    const int nbk = (N + 255) / 256;

    char* ws = (char*)d_ws;
    size_t off = 0;
    auto alloc = [&](size_t bytes) -> void* {
        void* p = ws + off;
        off = (off + bytes + 255) & ~(size_t)255;
        return p;
    };
    __half2* lr   = (__half2*)alloc((size_t)N * CH * 4);
    __half2* rf   = (__half2*)alloc((size_t)N * CH * 4);
    int*   deg    = (int*)alloc((size_t)N * 4);
    int*   bsum   = (int*)alloc((size_t)nbk * 4);
    int*   rowptr = (int*)alloc((size_t)(N + 1) * 4);
    int*   rank   = (int*)alloc((size_t)E * 4);
    int*   col    = (int*)alloc((size_t)E * 4);

    hipMemsetAsync(deg, 0, (size_t)N * 4, stream);
    proj_count_kernel<<<PROJ_BLOCKS + 2048, 256, 0, stream>>>(
        ndata, W1, b1, W2, b2, Wr, br, lr, out, dst, deg, rank, N, E);
    bsum_kernel<<<nbk, 256, 0, stream>>>(deg, bsum, N);
    bscan_kernel<<<1, 64, 0, stream>>>(bsum, nbk);
    apply_kernel<<<nbk, 256, 0, stream>>>(deg, bsum, rowptr, N, E);
    scatter_kernel<<<2048, 256, 0, stream>>>(src, dst, rank, rowptr, col, E);
    int nb = (N + 3) / 4;
    passA_kernel<<<nb, 256, 0, stream>>>(lr, rowptr, col, rf, N);
    passB_kernel<<<nb, 256, 0, stream>>>(rf, rowptr, col, m, out, N);
}